// Round 9
// baseline (459.170 us; speedup 1.0000x reference)
//
#include <hip/hip_runtime.h>
#include <hip/hip_bf16.h>

// ---------------------------------------------------------------------------
// AttentionBlock: B=8, L=1024, C=1024, H=8, ch=128.
// fp32 I/O, bf16 MFMA internal.  Head split is a free flat reinterpret.
// R8 lesson: scattered 2B global stores amplify HBM writes ~10x -- V^T goes
// through the LDS-staged transpose_head kernel (coalesced both sides).
// ---------------------------------------------------------------------------

typedef __attribute__((ext_vector_type(8))) short short8;
typedef __attribute__((ext_vector_type(4))) float f32x4;

#define QK_SCALE 0.29730177875068026f  // 128^-0.25

__device__ __forceinline__ float bf2f(ushort u) {
    union { float f; unsigned int i; } c; c.i = ((unsigned int)u) << 16; return c.f;
}
__device__ __forceinline__ ushort f2bf(float f) {
    union { float f; unsigned int i; } c; c.f = f;
    unsigned int x = c.i;
    return (ushort)((x + 0x7FFFu + ((x >> 16) & 1u)) >> 16);  // RNE
}

// async 16B global->LDS (m97; LDS dest must be wave-uniform base + lane*16)
__device__ __forceinline__ void gload_lds16(const ushort* g, ushort* l) {
    __builtin_amdgcn_global_load_lds(
        (const __attribute__((address_space(1))) unsigned int*)g,
        (__attribute__((address_space(3))) unsigned int*)l, 16, 0, 0);
}

// ---------------------------------------------------------------------------
// Prep kernel: LN row-per-wave (blocks 0..2047, 4 rows/block, no barriers)
// + w_qkv transpose tiles (2048..5119) + w_out transpose (5120..6143).
// ---------------------------------------------------------------------------
__global__ __launch_bounds__(256) void prep_kernel(
    const float* __restrict__ x, const float* __restrict__ g,
    const float* __restrict__ b, ushort* __restrict__ xn,
    const float* __restrict__ w_qkv, ushort* __restrict__ wqkvT,
    const float* __restrict__ w_out, ushort* __restrict__ woutT) {
    __shared__ ushort t[32][33];
    int bid = blockIdx.x;
    int tid = threadIdx.x;
    if (bid < 2048) {
        // ---- LayerNorm: one row per wave ----
        int w = tid >> 6, lane = tid & 63;
        int row = bid * 4 + w;
        const float* xr = x + (size_t)row * 1024;
        float v[4][4];
        float s1 = 0.f, s2 = 0.f;
#pragma unroll
        for (int j = 0; j < 4; j++) {
            float4 t4 = *(const float4*)(xr + lane * 4 + j * 256);
            v[j][0] = t4.x; v[j][1] = t4.y; v[j][2] = t4.z; v[j][3] = t4.w;
#pragma unroll
            for (int e = 0; e < 4; e++) { s1 += v[j][e]; s2 += v[j][e] * v[j][e]; }
        }
#pragma unroll
        for (int m = 32; m >= 1; m >>= 1) { s1 += __shfl_xor(s1, m); s2 += __shfl_xor(s2, m); }
        float mu = s1 * (1.0f / 1024.0f);
        float var = s2 * (1.0f / 1024.0f) - mu * mu;
        float rs = rsqrtf(var + 1e-5f);
#pragma unroll
        for (int j = 0; j < 4; j++) {
            int c0 = lane * 4 + j * 256;
            float4 gg = *(const float4*)(g + c0);
            float4 bb = *(const float4*)(b + c0);
            float gA[4] = {gg.x, gg.y, gg.z, gg.w};
            float bA[4] = {bb.x, bb.y, bb.z, bb.w};
            ushort o[4];
#pragma unroll
            for (int e = 0; e < 4; e++) o[e] = f2bf((v[j][e] - mu) * rs * gA[e] + bA[e]);
            uint2 pk;
            pk.x = (uint)o[0] | ((uint)o[1] << 16);
            pk.y = (uint)o[2] | ((uint)o[3] << 16);
            *(uint2*)(xn + (size_t)row * 1024 + c0) = pk;
        }
    } else {
        // ---- weight transpose tile ----
        const float* in; ushort* out; int R, Cc, bx, by;
        if (bid < 5120) {
            int tt = bid - 2048;
            in = w_qkv; out = wqkvT; R = 1024; Cc = 3072;
            bx = (tt % 96) * 32; by = (tt / 96) * 32;
        } else {
            int tt = bid - 5120;
            in = w_out; out = woutT; R = 1024; Cc = 1024;
            bx = (tt % 32) * 32; by = (tt / 32) * 32;
        }
        int tx = tid & 31, ty = tid >> 5;
#pragma unroll
        for (int j = 0; j < 32; j += 8)
            t[ty + j][tx] = f2bf(in[(size_t)(by + ty + j) * Cc + bx + tx]);
        __syncthreads();
#pragma unroll
        for (int j = 0; j < 32; j += 8)
            out[(size_t)(bx + ty + j) * R + by + tx] = t[tx][ty + j];
    }
}

// ---------------------------------------------------------------------------
// Per-head bf16 transpose: in [64][1024][128] -> out [64][128][1024]
// Coalesced reads and writes via 32x33 LDS tile.
// ---------------------------------------------------------------------------
__global__ __launch_bounds__(256) void transpose_head(
    const ushort* __restrict__ in, ushort* __restrict__ out) {
    __shared__ ushort t[32][33];
    int h = blockIdx.z;
    int j0 = blockIdx.y * 32;  // seq pos
    int d0 = blockIdx.x * 32;  // head dim
    int tx = threadIdx.x & 31, ty = threadIdx.x >> 5;
    const ushort* src = in + (size_t)h * 131072;
    ushort* dst = out + (size_t)h * 131072;
#pragma unroll
    for (int j = 0; j < 32; j += 8)
        t[ty + j][tx] = src[(size_t)(j0 + ty + j) * 128 + d0 + tx];
    __syncthreads();
#pragma unroll
    for (int j = 0; j < 32; j += 8)
        dst[(size_t)(d0 + ty + j) * 1024 + j0 + tx] = t[tx][ty + j];
}

// ---------------------------------------------------------------------------
// QKV GEMM: C[M,3072] = A[M,1024] @ Bt[3072,1024]^T, 128x128 tile, BK=64,
// XOR-8 chunk swizzle (conflict-free: SQ_LDS_BANK_CONFLICT=0 measured).
// launch_bounds(256,5): VGPR<=102 -> 5 blocks/CU (20 waves) vs 4.
// Epilogue: coalesced row-major q/k/v writes (v to scratch for transpose).
// ---------------------------------------------------------------------------
__global__ __launch_bounds__(256, 5) void gemm_qkv(
    const ushort* __restrict__ A, const ushort* __restrict__ Bt,
    const float* __restrict__ bias, ushort* __restrict__ out0,
    ushort* __restrict__ out1, ushort* __restrict__ out2) {
    const int K = 1024;
    __shared__ __align__(16) ushort As[128 * 64];  // 16 KB
    __shared__ __align__(16) ushort Bs[128 * 64];  // 16 KB

    int tid = threadIdx.x;
    int lane = tid & 63, w = tid >> 6;
    int l15 = lane & 15, q4 = lane >> 4;
    int wr = (w >> 1) * 64, wc = (w & 1) * 64;
    int rowBase = blockIdx.y * 128, colBase = blockIdx.x * 128;

    // persistent staging pointers (incremented by BK each kt)
    const ushort* aS[4]; const ushort* bS[4];
    ushort* aD[4]; ushort* bD[4];
#pragma unroll
    for (int i = 0; i < 4; i++) {
        int linear = i * 256 + w * 64 + lane;  // 16B chunk id, 0..1023
        int r = linear >> 3;
        int l = (linear & 7) ^ (r & 7);
        aS[i] = A + (size_t)(rowBase + r) * K + l * 8;
        bS[i] = Bt + (size_t)(colBase + r) * K + l * 8;
        aD[i] = &As[linear * 8];
        bD[i] = &Bs[linear * 8];
    }

    f32x4 acc[4][4];
    f32x4 zero = {0.f, 0.f, 0.f, 0.f};
#pragma unroll
    for (int mi = 0; mi < 4; mi++)
#pragma unroll
        for (int ni = 0; ni < 4; ni++) acc[mi][ni] = zero;

    for (int kt = 0; kt < 16; kt++) {
        __syncthreads();
#pragma unroll
        for (int i = 0; i < 4; i++) {
            gload_lds16(aS[i], aD[i]);
            gload_lds16(bS[i], bD[i]);
            aS[i] += 64; bS[i] += 64;
        }
        __syncthreads();

#pragma unroll
        for (int kk = 0; kk < 2; kk++) {
            short8 aF[4], bF[4];
#pragma unroll
            for (int mi = 0; mi < 4; mi++) {
                int r = wr + mi * 16 + l15;
                aF[mi] = *(const short8*)&As[r * 64 + ((kk * 4 + q4) ^ (r & 7)) * 8];
            }
#pragma unroll
            for (int ni = 0; ni < 4; ni++) {
                int r = wc + ni * 16 + l15;
                bF[ni] = *(const short8*)&Bs[r * 64 + ((kk * 4 + q4) ^ (r & 7)) * 8];
            }
#pragma unroll
            for (int mi = 0; mi < 4; mi++)
#pragma unroll
                for (int ni = 0; ni < 4; ni++)
                    acc[mi][ni] = __builtin_amdgcn_mfma_f32_16x16x32_bf16(
                        aF[mi], bF[ni], acc[mi][ni], 0, 0, 0);
        }
    }

    // C layout: col = lane&15, row = (lane>>4)*4 + r  [m89/m91]
    // ni-outer: dst/scale/cc uniform over (mi,r).
#pragma unroll
    for (int ni = 0; ni < 4; ni++) {
        int col = colBase + wc + ni * 16 + l15;
        float bv = bias[col];
        float sc = (col < 2048) ? QK_SCALE : 1.0f;
        int bsel = col >> 10, cc = col & 1023;
        ushort* dst = (bsel == 0) ? out0 : ((bsel == 1) ? out1 : out2);
#pragma unroll
        for (int mi = 0; mi < 4; mi++) {
            f32x4 a = acc[mi][ni];
#pragma unroll
            for (int r = 0; r < 4; r++) {
                int row = rowBase + wr + mi * 16 + q4 * 4 + r;
                dst[(size_t)row * 1024 + cc] = f2bf((a[r] + bv) * sc);
            }
        }
    }
}

// ---------------------------------------------------------------------------
// Out-proj GEMM: outf[M,1024] = A[M,1024] @ Bt[1024,1024]^T + bias + resid.
// 64x128 tile, BK=64, XOR-8 swizzle, grid (8,128)=1024 blocks, 24 KB LDS.
// launch_bounds(256,5) for 5 blocks/CU.
// ---------------------------------------------------------------------------
__global__ __launch_bounds__(256, 5) void gemm_out(
    const ushort* __restrict__ A, const ushort* __restrict__ Bt,
    const float* __restrict__ bias, const ushort* __restrict__ resid,
    float* __restrict__ outf) {
    const int K = 1024;
    __shared__ __align__(16) ushort As[64 * 64];    //  8 KB, 512 chunks
    __shared__ __align__(16) ushort Bs[128 * 64];   // 16 KB, 1024 chunks

    int tid = threadIdx.x;
    int lane = tid & 63, w = tid >> 6;
    int l15 = lane & 15, q4 = lane >> 4;
    int wr = (w >> 1) * 32, wc = (w & 1) * 64;
    int rowBase = blockIdx.y * 64, colBase = blockIdx.x * 128;

    const ushort* src[6]; ushort* dstp[6];
#pragma unroll
    for (int i = 0; i < 6; i++) {
        int id = i * 256 + w * 64 + lane;  // 0..1535
        if (id < 512) {
            int r = id >> 3, l = (id & 7) ^ ((id >> 3) & 7);
            src[i] = A + (size_t)(rowBase + r) * K + l * 8;
            dstp[i] = &As[id * 8];
        } else {
            int idb = id - 512;
            int r = idb >> 3, l = (idb & 7) ^ ((idb >> 3) & 7);
            src[i] = Bt + (size_t)(colBase + r) * K + l * 8;
            dstp[i] = &Bs[idb * 8];
        }
    }

    f32x4 acc[2][4];
    f32x4 zero = {0.f, 0.f, 0.f, 0.f};
#pragma unroll
    for (int mi = 0; mi < 2; mi++)
#pragma unroll
        for (int ni = 0; ni < 4; ni++) acc[mi][ni] = zero;

    for (int kt = 0; kt < 16; kt++) {
        __syncthreads();
#pragma unroll
        for (int i = 0; i < 6; i++) {
            gload_lds16(src[i], dstp[i]);
            src[i] += 64;
        }
        __syncthreads();

#pragma unroll
        for (int kk = 0; kk < 2; kk++) {
            short8 aF[2], bF[4];
#pragma unroll
            for (int mi = 0; mi < 2; mi++) {
                int r = wr + mi * 16 + l15;
                aF[mi] = *(const short8*)&As[r * 64 + ((kk * 4 + q4) ^ (r & 7)) * 8];
            }
#pragma unroll
            for (int ni = 0; ni < 4; ni++) {
                int r = wc + ni * 16 + l15;
                bF[ni] = *(const short8*)&Bs[r * 64 + ((kk * 4 + q4) ^ (r & 7)) * 8];
            }
#pragma unroll
            for (int mi = 0; mi < 2; mi++)
#pragma unroll
                for (int ni = 0; ni < 4; ni++)
                    acc[mi][ni] = __builtin_amdgcn_mfma_f32_16x16x32_bf16(
                        aF[mi], bF[ni], acc[mi][ni], 0, 0, 0);
        }
    }

#pragma unroll
    for (int ni = 0; ni < 4; ni++) {
        int col = colBase + wc + ni * 16 + l15;
        float bv = bias[col];
#pragma unroll
        for (int mi = 0; mi < 2; mi++) {
            f32x4 a = acc[mi][ni];
#pragma unroll
            for (int r = 0; r < 4; r++) {
                int row = rowBase + wr + mi * 16 + q4 * 4 + r;
                outf[(size_t)row * 1024 + col] =
                    a[r] + bv + bf2f(resid[(size_t)row * 1024 + col]);
            }
        }
    }
}

// ---------------------------------------------------------------------------
// Attention v6: one block = (head g, 64 q-rows); 4 waves x 16q; 256 thr;
// LDS 40 KB -> 4 blocks/CU, 16 waves/CU.  No-max softmax, deferred reduce.
//  - Q fragments in registers
//  - Ks [64 key][128 d], XOR-16 chunk swizzle, global_load_lds staged
//  - Vt [128 d][64 key], XOR-8 chunk swizzle, NOW global_load_lds staged
//    (swizzle applied on the global-address side; LDS dest lane-linear)
//  - Ps [64 q][64 key],  XOR-8 chunk swizzle, wave-private
// ---------------------------------------------------------------------------
__global__ __launch_bounds__(256, 4) void attn_kernel(
    const ushort* __restrict__ qb, const ushort* __restrict__ kb,
    const ushort* __restrict__ vt, ushort* __restrict__ ob) {
    int g = blockIdx.x >> 4;       // head 0..63
    int qblk = blockIdx.x & 15;    // 64-row q block
    const ushort* Qh = qb + (size_t)g * 131072;
    const ushort* Kh = kb + (size_t)g * 131072;
    const ushort* Vh = vt + (size_t)g * 131072;  // [128 d][1024 key]

    __shared__ __align__(16) ushort Ks[64 * 128];  // 16 KB
    __shared__ __align__(16) ushort Vt[128 * 64];  // 16 KB
    __shared__ __align__(16) ushort Ps[64 * 64];   //  8 KB

    int tid = threadIdx.x, lane = tid & 63, w = tid >> 6;
    int l15 = lane & 15, q4 = lane >> 4;
    int q0 = qblk * 64;

    // Q A-fragments: A[m=l15][k = ks*32 + q4*8 + j]
    short8 qf[4];
#pragma unroll
    for (int ks = 0; ks < 4; ks++)
        qf[ks] = *(const short8*)&Qh[(size_t)(q0 + w * 16 + l15) * 128 + ks * 32 + q4 * 8];

    f32x4 zero = {0.f, 0.f, 0.f, 0.f};
    f32x4 o[8];
#pragma unroll
    for (int ni = 0; ni < 8; ni++) o[ni] = zero;
    float plsum[4] = {0.f, 0.f, 0.f, 0.f};

    for (int kt = 0; kt < 16; kt++) {
        __syncthreads();
        // Ks: phys chunk p in key-row r holds logical chunk l = p ^ (r&15)
#pragma unroll
        for (int i = 0; i < 4; i++) {
            int linear = i * 256 + w * 64 + lane;
            int r = linear >> 4, p = linear & 15;
            int l = p ^ (r & 15);
            gload_lds16(&Kh[(size_t)(kt * 64 + r) * 128 + l * 8], &Ks[linear * 8]);
        }
        // Vt: phys chunk p in d-row holds logical chunk c = p ^ (d&7)
#pragma unroll
        for (int i = 0; i < 4; i++) {
            int linear = i * 256 + w * 64 + lane;   // 0..1023
            int d = linear >> 3, p = linear & 7;
            int c = p ^ (d & 7);
            gload_lds16(&Vh[(size_t)d * 1024 + kt * 64 + c * 8], &Vt[linear * 8]);
        }
        __syncthreads();

        // S = Q K^T : 16q x 64key per wave
        f32x4 sacc[4];
#pragma unroll
        for (int ni = 0; ni < 4; ni++) sacc[ni] = zero;
#pragma unroll
        for (int ks = 0; ks < 4; ks++) {
#pragma unroll
            for (int ni = 0; ni < 4; ni++) {
                int r = ni * 16 + l15;
                int p = (ks * 4 + q4) ^ (r & 15);
                short8 bF = *(const short8*)&Ks[r * 128 + p * 8];
                sacc[ni] = __builtin_amdgcn_mfma_f32_16x16x32_bf16(
                    qf[ks], bF, sacc[ni], 0, 0, 0);
            }
        }

        // P = exp(S) -> Ps (swizzled); accumulate per-lane partial row sums
#pragma unroll
        for (int ni = 0; ni < 4; ni++) {
#pragma unroll
            for (int r = 0; r < 4; r++) {
                float pv = __expf(sacc[ni][r]);
                plsum[r] += pv;
                int qloc = w * 16 + q4 * 4 + r;
                int key = ni * 16 + l15;
                int pc = (key >> 3) ^ (qloc & 7);
                Ps[qloc * 64 + pc * 8 + (key & 7)] = f2bf(pv);
            }
        }

        // O += P V  (wave-private Ps rows; same-wave RAW handled by waitcnt)
#pragma unroll
        for (int ks2 = 0; ks2 < 2; ks2++) {
            int c = ks2 * 4 + q4;
            short8 aF = *(const short8*)&Ps[(w * 16 + l15) * 64 + (c ^ (l15 & 7)) * 8];
#pragma unroll
            for (int ni = 0; ni < 8; ni++) {
                int d = ni * 16 + l15;
                short8 bF = *(const short8*)&Vt[d * 64 + (c ^ (d & 7)) * 8];
                o[ni] = __builtin_amdgcn_mfma_f32_16x16x32_bf16(aF, bF, o[ni], 0, 0, 0);
            }
        }
    }

    // row sums: reduce per-lane partials over the 16 l15-lanes
#pragma unroll
    for (int r = 0; r < 4; r++) {
#pragma unroll
        for (int m = 1; m < 16; m <<= 1) plsum[r] += __shfl_xor(plsum[r], m, 16);
    }
    float inv[4];
#pragma unroll
    for (int r = 0; r < 4; r++) inv[r] = 1.0f / plsum[r];
#pragma unroll
    for (int ni = 0; ni < 8; ni++)
#pragma unroll
        for (int r = 0; r < 4; r++) {
            int qrow = q0 + w * 16 + q4 * 4 + r;
            ob[(size_t)g * 131072 + (size_t)qrow * 128 + ni * 16 + l15] =
                f2bf(o[ni][r] * inv[r]);
        }
}

// ---------------------------------------------------------------------------
extern "C" void kernel_launch(void* const* d_in, const int* in_sizes, int n_in,
                              void* d_out, int out_size, void* d_ws, size_t ws_size,
                              hipStream_t stream) {
    const float* x     = (const float*)d_in[0];
    const float* ln_g  = (const float*)d_in[1];
    const float* ln_b  = (const float*)d_in[2];
    const float* w_qkv = (const float*)d_in[3];
    const float* b_qkv = (const float*)d_in[4];
    const float* w_out = (const float*)d_in[5];
    const float* b_out = (const float*)d_in[6];
    float* out = (float*)d_out;

    const size_t MC = 8192ull * 1024ull;  // 8.39M elems
    ushort* xn    = (ushort*)d_ws;
    ushort* wqkvT = xn + MC;
    ushort* woutT = wqkvT + 3072ull * 1024ull;
    ushort* qbuf  = woutT + 1024ull * 1024ull;
    ushort* kbuf  = qbuf + MC;
    ushort* vtbuf = kbuf + MC;        // V^T [64 heads][128 d][1024 seq]
    ushort* attnb = vtbuf + MC;       // scratch for raw V, then attn output
    // total: 46.14M ushorts = 92.3 MB (same layout as passing rounds 2-7)

    prep_kernel<<<6144, 256, 0, stream>>>(x, ln_g, ln_b, xn, w_qkv, wqkvT, w_out, woutT);
    // q,k -> qbuf,kbuf ; v -> attnb (scratch, row-major coalesced)
    gemm_qkv<<<dim3(24, 64), 256, 0, stream>>>(xn, wqkvT, b_qkv, qbuf, kbuf, attnb);
    transpose_head<<<dim3(4, 32, 64), 256, 0, stream>>>(attnb, vtbuf);
    attn_kernel<<<1024, 256, 0, stream>>>(qbuf, kbuf, vtbuf, attnb);
    gemm_out<<<dim3(8, 128), 256, 0, stream>>>(attnb, woutT, b_out, xn, out);
}

// Round 10
// 260.866 us; speedup vs baseline: 1.7602x; 1.7602x over previous
//
#include <hip/hip_runtime.h>
#include <hip/hip_bf16.h>

// ---------------------------------------------------------------------------
// AttentionBlock: B=8, L=1024, C=1024, H=8, ch=128.
// fp32 I/O, bf16 MFMA internal.  Head split is a free flat reinterpret.
// R8 lesson: scattered 2B global stores amplify HBM writes ~10x.
// R9 lesson: launch_bounds occupancy floors past VGPR need -> scratch spills
// (VGPR_Count 104->48, 1 GB HBM spill traffic).  GEMMs keep natural bounds.
// ---------------------------------------------------------------------------

typedef __attribute__((ext_vector_type(8))) short short8;
typedef __attribute__((ext_vector_type(4))) float f32x4;

#define QK_SCALE 0.29730177875068026f  // 128^-0.25

__device__ __forceinline__ float bf2f(ushort u) {
    union { float f; unsigned int i; } c; c.i = ((unsigned int)u) << 16; return c.f;
}
__device__ __forceinline__ ushort f2bf(float f) {
    union { float f; unsigned int i; } c; c.f = f;
    unsigned int x = c.i;
    return (ushort)((x + 0x7FFFu + ((x >> 16) & 1u)) >> 16);  // RNE
}

// async 16B global->LDS (m97; LDS dest must be wave-uniform base + lane*16)
__device__ __forceinline__ void gload_lds16(const ushort* g, ushort* l) {
    __builtin_amdgcn_global_load_lds(
        (const __attribute__((address_space(1))) unsigned int*)g,
        (__attribute__((address_space(3))) unsigned int*)l, 16, 0, 0);
}

// ---------------------------------------------------------------------------
// Prep kernel: LN row-per-wave (blocks 0..2047, 4 rows/block, no barriers)
// + w_qkv transpose tiles (2048..5119) + w_out transpose (5120..6143).
// ---------------------------------------------------------------------------
__global__ __launch_bounds__(256) void prep_kernel(
    const float* __restrict__ x, const float* __restrict__ g,
    const float* __restrict__ b, ushort* __restrict__ xn,
    const float* __restrict__ w_qkv, ushort* __restrict__ wqkvT,
    const float* __restrict__ w_out, ushort* __restrict__ woutT) {
    __shared__ ushort t[32][33];
    int bid = blockIdx.x;
    int tid = threadIdx.x;
    if (bid < 2048) {
        // ---- LayerNorm: one row per wave ----
        int w = tid >> 6, lane = tid & 63;
        int row = bid * 4 + w;
        const float* xr = x + (size_t)row * 1024;
        float v[4][4];
        float s1 = 0.f, s2 = 0.f;
#pragma unroll
        for (int j = 0; j < 4; j++) {
            float4 t4 = *(const float4*)(xr + lane * 4 + j * 256);
            v[j][0] = t4.x; v[j][1] = t4.y; v[j][2] = t4.z; v[j][3] = t4.w;
#pragma unroll
            for (int e = 0; e < 4; e++) { s1 += v[j][e]; s2 += v[j][e] * v[j][e]; }
        }
#pragma unroll
        for (int m = 32; m >= 1; m >>= 1) { s1 += __shfl_xor(s1, m); s2 += __shfl_xor(s2, m); }
        float mu = s1 * (1.0f / 1024.0f);
        float var = s2 * (1.0f / 1024.0f) - mu * mu;
        float rs = rsqrtf(var + 1e-5f);
#pragma unroll
        for (int j = 0; j < 4; j++) {
            int c0 = lane * 4 + j * 256;
            float4 gg = *(const float4*)(g + c0);
            float4 bb = *(const float4*)(b + c0);
            float gA[4] = {gg.x, gg.y, gg.z, gg.w};
            float bA[4] = {bb.x, bb.y, bb.z, bb.w};
            ushort o[4];
#pragma unroll
            for (int e = 0; e < 4; e++) o[e] = f2bf((v[j][e] - mu) * rs * gA[e] + bA[e]);
            uint2 pk;
            pk.x = (uint)o[0] | ((uint)o[1] << 16);
            pk.y = (uint)o[2] | ((uint)o[3] << 16);
            *(uint2*)(xn + (size_t)row * 1024 + c0) = pk;
        }
    } else {
        // ---- weight transpose tile ----
        const float* in; ushort* out; int R, Cc, bx, by;
        if (bid < 5120) {
            int tt = bid - 2048;
            in = w_qkv; out = wqkvT; R = 1024; Cc = 3072;
            bx = (tt % 96) * 32; by = (tt / 96) * 32;
        } else {
            int tt = bid - 5120;
            in = w_out; out = woutT; R = 1024; Cc = 1024;
            bx = (tt % 32) * 32; by = (tt / 32) * 32;
        }
        int tx = tid & 31, ty = tid >> 5;
#pragma unroll
        for (int j = 0; j < 32; j += 8)
            t[ty + j][tx] = f2bf(in[(size_t)(by + ty + j) * Cc + bx + tx]);
        __syncthreads();
#pragma unroll
        for (int j = 0; j < 32; j += 8)
            out[(size_t)(bx + ty + j) * R + by + tx] = t[tx][ty + j];
    }
}

// ---------------------------------------------------------------------------
// Per-head bf16 transpose: in [64][1024][128] -> out [64][128][1024]
// Coalesced reads and writes via 32x33 LDS tile.
// ---------------------------------------------------------------------------
__global__ __launch_bounds__(256) void transpose_head(
    const ushort* __restrict__ in, ushort* __restrict__ out) {
    __shared__ ushort t[32][33];
    int h = blockIdx.z;
    int j0 = blockIdx.y * 32;  // seq pos
    int d0 = blockIdx.x * 32;  // head dim
    int tx = threadIdx.x & 31, ty = threadIdx.x >> 5;
    const ushort* src = in + (size_t)h * 131072;
    ushort* dst = out + (size_t)h * 131072;
#pragma unroll
    for (int j = 0; j < 32; j += 8)
        t[ty + j][tx] = src[(size_t)(j0 + ty + j) * 128 + d0 + tx];
    __syncthreads();
#pragma unroll
    for (int j = 0; j < 32; j += 8)
        dst[(size_t)(d0 + ty + j) * 1024 + j0 + tx] = t[tx][ty + j];
}

// ---------------------------------------------------------------------------
// QKV GEMM: C[M,3072] = A[M,1024] @ Bt[3072,1024]^T, 128x128 tile, BK=64,
// XOR-8 chunk swizzle (conflict-free: SQ_LDS_BANK_CONFLICT=0 measured).
// NO occupancy floor: needs ~104 VGPR; capping it spills acc to scratch (R9).
// ---------------------------------------------------------------------------
__global__ __launch_bounds__(256) void gemm_qkv(
    const ushort* __restrict__ A, const ushort* __restrict__ Bt,
    const float* __restrict__ bias, ushort* __restrict__ out0,
    ushort* __restrict__ out1, ushort* __restrict__ out2) {
    const int K = 1024;
    __shared__ __align__(16) ushort As[128 * 64];  // 16 KB
    __shared__ __align__(16) ushort Bs[128 * 64];  // 16 KB

    int tid = threadIdx.x;
    int lane = tid & 63, w = tid >> 6;
    int l15 = lane & 15, q4 = lane >> 4;
    int wr = (w >> 1) * 64, wc = (w & 1) * 64;
    int rowBase = blockIdx.y * 128, colBase = blockIdx.x * 128;

    // persistent staging pointers (incremented by BK each kt)
    const ushort* aS[4]; const ushort* bS[4];
    ushort* aD[4]; ushort* bD[4];
#pragma unroll
    for (int i = 0; i < 4; i++) {
        int linear = i * 256 + w * 64 + lane;  // 16B chunk id, 0..1023
        int r = linear >> 3;
        int l = (linear & 7) ^ (r & 7);
        aS[i] = A + (size_t)(rowBase + r) * K + l * 8;
        bS[i] = Bt + (size_t)(colBase + r) * K + l * 8;
        aD[i] = &As[linear * 8];
        bD[i] = &Bs[linear * 8];
    }

    f32x4 acc[4][4];
    f32x4 zero = {0.f, 0.f, 0.f, 0.f};
#pragma unroll
    for (int mi = 0; mi < 4; mi++)
#pragma unroll
        for (int ni = 0; ni < 4; ni++) acc[mi][ni] = zero;

    for (int kt = 0; kt < 16; kt++) {
        __syncthreads();
#pragma unroll
        for (int i = 0; i < 4; i++) {
            gload_lds16(aS[i], aD[i]);
            gload_lds16(bS[i], bD[i]);
            aS[i] += 64; bS[i] += 64;
        }
        __syncthreads();

#pragma unroll
        for (int kk = 0; kk < 2; kk++) {
            short8 aF[4], bF[4];
#pragma unroll
            for (int mi = 0; mi < 4; mi++) {
                int r = wr + mi * 16 + l15;
                aF[mi] = *(const short8*)&As[r * 64 + ((kk * 4 + q4) ^ (r & 7)) * 8];
            }
#pragma unroll
            for (int ni = 0; ni < 4; ni++) {
                int r = wc + ni * 16 + l15;
                bF[ni] = *(const short8*)&Bs[r * 64 + ((kk * 4 + q4) ^ (r & 7)) * 8];
            }
#pragma unroll
            for (int mi = 0; mi < 4; mi++)
#pragma unroll
                for (int ni = 0; ni < 4; ni++)
                    acc[mi][ni] = __builtin_amdgcn_mfma_f32_16x16x32_bf16(
                        aF[mi], bF[ni], acc[mi][ni], 0, 0, 0);
        }
    }

    // C layout: col = lane&15, row = (lane>>4)*4 + r  [m89/m91]
    // ni-outer: dst/scale/cc uniform over (mi,r).
#pragma unroll
    for (int ni = 0; ni < 4; ni++) {
        int col = colBase + wc + ni * 16 + l15;
        float bv = bias[col];
        float sc = (col < 2048) ? QK_SCALE : 1.0f;
        int bsel = col >> 10, cc = col & 1023;
        ushort* dst = (bsel == 0) ? out0 : ((bsel == 1) ? out1 : out2);
#pragma unroll
        for (int mi = 0; mi < 4; mi++) {
            f32x4 a = acc[mi][ni];
#pragma unroll
            for (int r = 0; r < 4; r++) {
                int row = rowBase + wr + mi * 16 + q4 * 4 + r;
                dst[(size_t)row * 1024 + cc] = f2bf((a[r] + bv) * sc);
            }
        }
    }
}

// ---------------------------------------------------------------------------
// Out-proj GEMM: outf[M,1024] = A[M,1024] @ Bt[1024,1024]^T + bias + resid.
// 64x128 tile, BK=64, XOR-8 swizzle, grid (8,128)=1024 blocks, 24 KB LDS.
// (256,4) was measured spill-free in R7/R8.
// ---------------------------------------------------------------------------
__global__ __launch_bounds__(256, 4) void gemm_out(
    const ushort* __restrict__ A, const ushort* __restrict__ Bt,
    const float* __restrict__ bias, const ushort* __restrict__ resid,
    float* __restrict__ outf) {
    const int K = 1024;
    __shared__ __align__(16) ushort As[64 * 64];    //  8 KB, 512 chunks
    __shared__ __align__(16) ushort Bs[128 * 64];   // 16 KB, 1024 chunks

    int tid = threadIdx.x;
    int lane = tid & 63, w = tid >> 6;
    int l15 = lane & 15, q4 = lane >> 4;
    int wr = (w >> 1) * 32, wc = (w & 1) * 64;
    int rowBase = blockIdx.y * 64, colBase = blockIdx.x * 128;

    const ushort* src[6]; ushort* dstp[6];
#pragma unroll
    for (int i = 0; i < 6; i++) {
        int id = i * 256 + w * 64 + lane;  // 0..1535
        if (id < 512) {
            int r = id >> 3, l = (id & 7) ^ ((id >> 3) & 7);
            src[i] = A + (size_t)(rowBase + r) * K + l * 8;
            dstp[i] = &As[id * 8];
        } else {
            int idb = id - 512;
            int r = idb >> 3, l = (idb & 7) ^ ((idb >> 3) & 7);
            src[i] = Bt + (size_t)(colBase + r) * K + l * 8;
            dstp[i] = &Bs[idb * 8];
        }
    }

    f32x4 acc[2][4];
    f32x4 zero = {0.f, 0.f, 0.f, 0.f};
#pragma unroll
    for (int mi = 0; mi < 2; mi++)
#pragma unroll
        for (int ni = 0; ni < 4; ni++) acc[mi][ni] = zero;

    for (int kt = 0; kt < 16; kt++) {
        __syncthreads();
#pragma unroll
        for (int i = 0; i < 6; i++) {
            gload_lds16(src[i], dstp[i]);
            src[i] += 64;
        }
        __syncthreads();

#pragma unroll
        for (int kk = 0; kk < 2; kk++) {
            short8 aF[2], bF[4];
#pragma unroll
            for (int mi = 0; mi < 2; mi++) {
                int r = wr + mi * 16 + l15;
                aF[mi] = *(const short8*)&As[r * 64 + ((kk * 4 + q4) ^ (r & 7)) * 8];
            }
#pragma unroll
            for (int ni = 0; ni < 4; ni++) {
                int r = wc + ni * 16 + l15;
                bF[ni] = *(const short8*)&Bs[r * 64 + ((kk * 4 + q4) ^ (r & 7)) * 8];
            }
#pragma unroll
            for (int mi = 0; mi < 2; mi++)
#pragma unroll
                for (int ni = 0; ni < 4; ni++)
                    acc[mi][ni] = __builtin_amdgcn_mfma_f32_16x16x32_bf16(
                        aF[mi], bF[ni], acc[mi][ni], 0, 0, 0);
        }
    }

#pragma unroll
    for (int ni = 0; ni < 4; ni++) {
        int col = colBase + wc + ni * 16 + l15;
        float bv = bias[col];
#pragma unroll
        for (int mi = 0; mi < 2; mi++) {
            f32x4 a = acc[mi][ni];
#pragma unroll
            for (int r = 0; r < 4; r++) {
                int row = rowBase + wr + mi * 16 + q4 * 4 + r;
                outf[(size_t)row * 1024 + col] =
                    a[r] + bv + bf2f(resid[(size_t)row * 1024 + col]);
            }
        }
    }
}

// ---------------------------------------------------------------------------
// Attention v6: one block = (head g, 64 q-rows); 4 waves x 16q; 256 thr;
// LDS 40 KB -> 4 blocks/CU, 16 waves/CU.  No-max softmax, deferred reduce.
//  - Q fragments in registers
//  - Ks [64 key][128 d], XOR-16 chunk swizzle, global_load_lds staged
//  - Vt [128 d][64 key], XOR-8 chunk swizzle, global_load_lds staged
//  - Ps [64 q][64 key],  XOR-8 chunk swizzle, wave-private
// ---------------------------------------------------------------------------
__global__ __launch_bounds__(256, 4) void attn_kernel(
    const ushort* __restrict__ qb, const ushort* __restrict__ kb,
    const ushort* __restrict__ vt, ushort* __restrict__ ob) {
    int g = blockIdx.x >> 4;       // head 0..63
    int qblk = blockIdx.x & 15;    // 64-row q block
    const ushort* Qh = qb + (size_t)g * 131072;
    const ushort* Kh = kb + (size_t)g * 131072;
    const ushort* Vh = vt + (size_t)g * 131072;  // [128 d][1024 key]

    __shared__ __align__(16) ushort Ks[64 * 128];  // 16 KB
    __shared__ __align__(16) ushort Vt[128 * 64];  // 16 KB
    __shared__ __align__(16) ushort Ps[64 * 64];   //  8 KB

    int tid = threadIdx.x, lane = tid & 63, w = tid >> 6;
    int l15 = lane & 15, q4 = lane >> 4;
    int q0 = qblk * 64;

    // Q A-fragments: A[m=l15][k = ks*32 + q4*8 + j]
    short8 qf[4];
#pragma unroll
    for (int ks = 0; ks < 4; ks++)
        qf[ks] = *(const short8*)&Qh[(size_t)(q0 + w * 16 + l15) * 128 + ks * 32 + q4 * 8];

    f32x4 zero = {0.f, 0.f, 0.f, 0.f};
    f32x4 o[8];
#pragma unroll
    for (int ni = 0; ni < 8; ni++) o[ni] = zero;
    float plsum[4] = {0.f, 0.f, 0.f, 0.f};

    for (int kt = 0; kt < 16; kt++) {
        __syncthreads();
        // Ks: phys chunk p in key-row r holds logical chunk l = p ^ (r&15)
#pragma unroll
        for (int i = 0; i < 4; i++) {
            int linear = i * 256 + w * 64 + lane;
            int r = linear >> 4, p = linear & 15;
            int l = p ^ (r & 15);
            gload_lds16(&Kh[(size_t)(kt * 64 + r) * 128 + l * 8], &Ks[linear * 8]);
        }
        // Vt: phys chunk p in d-row holds logical chunk c = p ^ (d&7)
#pragma unroll
        for (int i = 0; i < 4; i++) {
            int linear = i * 256 + w * 64 + lane;   // 0..1023
            int d = linear >> 3, p = linear & 7;
            int c = p ^ (d & 7);
            gload_lds16(&Vh[(size_t)d * 1024 + kt * 64 + c * 8], &Vt[linear * 8]);
        }
        __syncthreads();

        // S = Q K^T : 16q x 64key per wave
        f32x4 sacc[4];
#pragma unroll
        for (int ni = 0; ni < 4; ni++) sacc[ni] = zero;
#pragma unroll
        for (int ks = 0; ks < 4; ks++) {
#pragma unroll
            for (int ni = 0; ni < 4; ni++) {
                int r = ni * 16 + l15;
                int p = (ks * 4 + q4) ^ (r & 15);
                short8 bF = *(const short8*)&Ks[r * 128 + p * 8];
                sacc[ni] = __builtin_amdgcn_mfma_f32_16x16x32_bf16(
                    qf[ks], bF, sacc[ni], 0, 0, 0);
            }
        }

        // P = exp(S) -> Ps (swizzled); accumulate per-lane partial row sums
#pragma unroll
        for (int ni = 0; ni < 4; ni++) {
#pragma unroll
            for (int r = 0; r < 4; r++) {
                float pv = __expf(sacc[ni][r]);
                plsum[r] += pv;
                int qloc = w * 16 + q4 * 4 + r;
                int key = ni * 16 + l15;
                int pc = (key >> 3) ^ (qloc & 7);
                Ps[qloc * 64 + pc * 8 + (key & 7)] = f2bf(pv);
            }
        }

        // O += P V  (wave-private Ps rows; same-wave RAW handled by waitcnt)
#pragma unroll
        for (int ks2 = 0; ks2 < 2; ks2++) {
            int c = ks2 * 4 + q4;
            short8 aF = *(const short8*)&Ps[(w * 16 + l15) * 64 + (c ^ (l15 & 7)) * 8];
#pragma unroll
            for (int ni = 0; ni < 8; ni++) {
                int d = ni * 16 + l15;
                short8 bF = *(const short8*)&Vt[d * 64 + (c ^ (d & 7)) * 8];
                o[ni] = __builtin_amdgcn_mfma_f32_16x16x32_bf16(aF, bF, o[ni], 0, 0, 0);
            }
        }
    }

    // row sums: reduce per-lane partials over the 16 l15-lanes
#pragma unroll
    for (int r = 0; r < 4; r++) {
#pragma unroll
        for (int m = 1; m < 16; m <<= 1) plsum[r] += __shfl_xor(plsum[r], m, 16);
    }
    float inv[4];
#pragma unroll
    for (int r = 0; r < 4; r++) inv[r] = 1.0f / plsum[r];
#pragma unroll
    for (int ni = 0; ni < 8; ni++)
#pragma unroll
        for (int r = 0; r < 4; r++) {
            int qrow = q0 + w * 16 + q4 * 4 + r;
            ob[(size_t)g * 131072 + (size_t)qrow * 128 + ni * 16 + l15] =
                f2bf(o[ni][r] * inv[r]);
        }
}

// ---------------------------------------------------------------------------
extern "C" void kernel_launch(void* const* d_in, const int* in_sizes, int n_in,
                              void* d_out, int out_size, void* d_ws, size_t ws_size,
                              hipStream_t stream) {
    const float* x     = (const float*)d_in[0];
    const float* ln_g  = (const float*)d_in[1];
    const float* ln_b  = (const float*)d_in[2];
    const float* w_qkv = (const float*)d_in[3];
    const float* b_qkv = (const float*)d_in[4];
    const float* w_out = (const float*)d_in[5];
    const float* b_out = (const float*)d_in[6];
    float* out = (float*)d_out;

    const size_t MC = 8192ull * 1024ull;  // 8.39M elems
    ushort* xn    = (ushort*)d_ws;
    ushort* wqkvT = xn + MC;
    ushort* woutT = wqkvT + 3072ull * 1024ull;
    ushort* qbuf  = woutT + 1024ull * 1024ull;
    ushort* kbuf  = qbuf + MC;
    ushort* vtbuf = kbuf + MC;        // V^T [64 heads][128 d][1024 seq]
    ushort* attnb = vtbuf + MC;       // scratch for raw V, then attn output
    // total: 46.14M ushorts = 92.3 MB (same layout as passing rounds 2-8)

    prep_kernel<<<6144, 256, 0, stream>>>(x, ln_g, ln_b, xn, w_qkv, wqkvT, w_out, woutT);
    // q,k -> qbuf,kbuf ; v -> attnb (scratch, row-major coalesced)
    gemm_qkv<<<dim3(24, 64), 256, 0, stream>>>(xn, wqkvT, b_qkv, qbuf, kbuf, attnb);
    transpose_head<<<dim3(4, 32, 64), 256, 0, stream>>>(attnb, vtbuf);
    attn_kernel<<<1024, 256, 0, stream>>>(qbuf, kbuf, vtbuf, attnb);
    gemm_out<<<dim3(8, 128), 256, 0, stream>>>(attnb, woutT, b_out, xn, out);
}

// Round 11
// 250.501 us; speedup vs baseline: 1.8330x; 1.0414x over previous
//
#include <hip/hip_runtime.h>
#include <hip/hip_bf16.h>

// ---------------------------------------------------------------------------
// AttentionBlock: B=8, L=1024, C=1024, H=8, ch=128.
// fp32 I/O, bf16 MFMA internal.  Head split is a free flat reinterpret.
// R8 lesson: scattered 2B global stores amplify HBM writes ~10x.
// R9 lesson: launch_bounds floors past VGPR need -> scratch spills (1 GB HBM).
// R11: attn blocks widened to 512 thr / 8 waves sharing one K/V staging.
// ---------------------------------------------------------------------------

typedef __attribute__((ext_vector_type(8))) short short8;
typedef __attribute__((ext_vector_type(4))) float f32x4;

#define QK_SCALE 0.29730177875068026f  // 128^-0.25

__device__ __forceinline__ float bf2f(ushort u) {
    union { float f; unsigned int i; } c; c.i = ((unsigned int)u) << 16; return c.f;
}
__device__ __forceinline__ ushort f2bf(float f) {
    union { float f; unsigned int i; } c; c.f = f;
    unsigned int x = c.i;
    return (ushort)((x + 0x7FFFu + ((x >> 16) & 1u)) >> 16);  // RNE
}

// async 16B global->LDS (m97; LDS dest must be wave-uniform base + lane*16)
__device__ __forceinline__ void gload_lds16(const ushort* g, ushort* l) {
    __builtin_amdgcn_global_load_lds(
        (const __attribute__((address_space(1))) unsigned int*)g,
        (__attribute__((address_space(3))) unsigned int*)l, 16, 0, 0);
}

// ---------------------------------------------------------------------------
// Prep kernel: LN row-per-wave (blocks 0..2047, 4 rows/block, no barriers)
// + w_qkv transpose tiles (2048..5119) + w_out transpose (5120..6143).
// ---------------------------------------------------------------------------
__global__ __launch_bounds__(256) void prep_kernel(
    const float* __restrict__ x, const float* __restrict__ g,
    const float* __restrict__ b, ushort* __restrict__ xn,
    const float* __restrict__ w_qkv, ushort* __restrict__ wqkvT,
    const float* __restrict__ w_out, ushort* __restrict__ woutT) {
    __shared__ ushort t[32][33];
    int bid = blockIdx.x;
    int tid = threadIdx.x;
    if (bid < 2048) {
        // ---- LayerNorm: one row per wave ----
        int w = tid >> 6, lane = tid & 63;
        int row = bid * 4 + w;
        const float* xr = x + (size_t)row * 1024;
        float v[4][4];
        float s1 = 0.f, s2 = 0.f;
#pragma unroll
        for (int j = 0; j < 4; j++) {
            float4 t4 = *(const float4*)(xr + lane * 4 + j * 256);
            v[j][0] = t4.x; v[j][1] = t4.y; v[j][2] = t4.z; v[j][3] = t4.w;
#pragma unroll
            for (int e = 0; e < 4; e++) { s1 += v[j][e]; s2 += v[j][e] * v[j][e]; }
        }
#pragma unroll
        for (int m = 32; m >= 1; m >>= 1) { s1 += __shfl_xor(s1, m); s2 += __shfl_xor(s2, m); }
        float mu = s1 * (1.0f / 1024.0f);
        float var = s2 * (1.0f / 1024.0f) - mu * mu;
        float rs = rsqrtf(var + 1e-5f);
#pragma unroll
        for (int j = 0; j < 4; j++) {
            int c0 = lane * 4 + j * 256;
            float4 gg = *(const float4*)(g + c0);
            float4 bb = *(const float4*)(b + c0);
            float gA[4] = {gg.x, gg.y, gg.z, gg.w};
            float bA[4] = {bb.x, bb.y, bb.z, bb.w};
            ushort o[4];
#pragma unroll
            for (int e = 0; e < 4; e++) o[e] = f2bf((v[j][e] - mu) * rs * gA[e] + bA[e]);
            uint2 pk;
            pk.x = (uint)o[0] | ((uint)o[1] << 16);
            pk.y = (uint)o[2] | ((uint)o[3] << 16);
            *(uint2*)(xn + (size_t)row * 1024 + c0) = pk;
        }
    } else {
        // ---- weight transpose tile ----
        const float* in; ushort* out; int R, Cc, bx, by;
        if (bid < 5120) {
            int tt = bid - 2048;
            in = w_qkv; out = wqkvT; R = 1024; Cc = 3072;
            bx = (tt % 96) * 32; by = (tt / 96) * 32;
        } else {
            int tt = bid - 5120;
            in = w_out; out = woutT; R = 1024; Cc = 1024;
            bx = (tt % 32) * 32; by = (tt / 32) * 32;
        }
        int tx = tid & 31, ty = tid >> 5;
#pragma unroll
        for (int j = 0; j < 32; j += 8)
            t[ty + j][tx] = f2bf(in[(size_t)(by + ty + j) * Cc + bx + tx]);
        __syncthreads();
#pragma unroll
        for (int j = 0; j < 32; j += 8)
            out[(size_t)(bx + ty + j) * R + by + tx] = t[tx][ty + j];
    }
}

// ---------------------------------------------------------------------------
// Per-head bf16 transpose: in [64][1024][128] -> out [64][128][1024]
// ---------------------------------------------------------------------------
__global__ __launch_bounds__(256) void transpose_head(
    const ushort* __restrict__ in, ushort* __restrict__ out) {
    __shared__ ushort t[32][33];
    int h = blockIdx.z;
    int j0 = blockIdx.y * 32;  // seq pos
    int d0 = blockIdx.x * 32;  // head dim
    int tx = threadIdx.x & 31, ty = threadIdx.x >> 5;
    const ushort* src = in + (size_t)h * 131072;
    ushort* dst = out + (size_t)h * 131072;
#pragma unroll
    for (int j = 0; j < 32; j += 8)
        t[ty + j][tx] = src[(size_t)(j0 + ty + j) * 128 + d0 + tx];
    __syncthreads();
#pragma unroll
    for (int j = 0; j < 32; j += 8)
        dst[(size_t)(d0 + ty + j) * 1024 + j0 + tx] = t[tx][ty + j];
}

// ---------------------------------------------------------------------------
// QKV GEMM: C[M,3072] = A[M,1024] @ Bt[3072,1024]^T, 128x128 tile, BK=64,
// XOR-8 chunk swizzle (conflict-free measured).  Natural bounds (R9 lesson).
// ---------------------------------------------------------------------------
__global__ __launch_bounds__(256) void gemm_qkv(
    const ushort* __restrict__ A, const ushort* __restrict__ Bt,
    const float* __restrict__ bias, ushort* __restrict__ out0,
    ushort* __restrict__ out1, ushort* __restrict__ out2) {
    const int K = 1024;
    __shared__ __align__(16) ushort As[128 * 64];  // 16 KB
    __shared__ __align__(16) ushort Bs[128 * 64];  // 16 KB

    int tid = threadIdx.x;
    int lane = tid & 63, w = tid >> 6;
    int l15 = lane & 15, q4 = lane >> 4;
    int wr = (w >> 1) * 64, wc = (w & 1) * 64;
    int rowBase = blockIdx.y * 128, colBase = blockIdx.x * 128;

    const ushort* aS[4]; const ushort* bS[4];
    ushort* aD[4]; ushort* bD[4];
#pragma unroll
    for (int i = 0; i < 4; i++) {
        int linear = i * 256 + w * 64 + lane;  // 16B chunk id, 0..1023
        int r = linear >> 3;
        int l = (linear & 7) ^ (r & 7);
        aS[i] = A + (size_t)(rowBase + r) * K + l * 8;
        bS[i] = Bt + (size_t)(colBase + r) * K + l * 8;
        aD[i] = &As[linear * 8];
        bD[i] = &Bs[linear * 8];
    }

    f32x4 acc[4][4];
    f32x4 zero = {0.f, 0.f, 0.f, 0.f};
#pragma unroll
    for (int mi = 0; mi < 4; mi++)
#pragma unroll
        for (int ni = 0; ni < 4; ni++) acc[mi][ni] = zero;

    for (int kt = 0; kt < 16; kt++) {
        __syncthreads();
#pragma unroll
        for (int i = 0; i < 4; i++) {
            gload_lds16(aS[i], aD[i]);
            gload_lds16(bS[i], bD[i]);
            aS[i] += 64; bS[i] += 64;
        }
        __syncthreads();

#pragma unroll
        for (int kk = 0; kk < 2; kk++) {
            short8 aF[4], bF[4];
#pragma unroll
            for (int mi = 0; mi < 4; mi++) {
                int r = wr + mi * 16 + l15;
                aF[mi] = *(const short8*)&As[r * 64 + ((kk * 4 + q4) ^ (r & 7)) * 8];
            }
#pragma unroll
            for (int ni = 0; ni < 4; ni++) {
                int r = wc + ni * 16 + l15;
                bF[ni] = *(const short8*)&Bs[r * 64 + ((kk * 4 + q4) ^ (r & 7)) * 8];
            }
#pragma unroll
            for (int mi = 0; mi < 4; mi++)
#pragma unroll
                for (int ni = 0; ni < 4; ni++)
                    acc[mi][ni] = __builtin_amdgcn_mfma_f32_16x16x32_bf16(
                        aF[mi], bF[ni], acc[mi][ni], 0, 0, 0);
        }
    }

    // C layout: col = lane&15, row = (lane>>4)*4 + r  [m89/m91]
#pragma unroll
    for (int ni = 0; ni < 4; ni++) {
        int col = colBase + wc + ni * 16 + l15;
        float bv = bias[col];
        float sc = (col < 2048) ? QK_SCALE : 1.0f;
        int bsel = col >> 10, cc = col & 1023;
        ushort* dst = (bsel == 0) ? out0 : ((bsel == 1) ? out1 : out2);
#pragma unroll
        for (int mi = 0; mi < 4; mi++) {
            f32x4 a = acc[mi][ni];
#pragma unroll
            for (int r = 0; r < 4; r++) {
                int row = rowBase + wr + mi * 16 + q4 * 4 + r;
                dst[(size_t)row * 1024 + cc] = f2bf((a[r] + bv) * sc);
            }
        }
    }
}

// ---------------------------------------------------------------------------
// Out-proj GEMM: outf[M,1024] = A[M,1024] @ Bt[1024,1024]^T + bias + resid.
// 64x128 tile, BK=64, XOR-8 swizzle, grid (8,128)=1024 blocks, 24 KB LDS.
// (256,4) measured spill-free.
// ---------------------------------------------------------------------------
__global__ __launch_bounds__(256, 4) void gemm_out(
    const ushort* __restrict__ A, const ushort* __restrict__ Bt,
    const float* __restrict__ bias, const ushort* __restrict__ resid,
    float* __restrict__ outf) {
    const int K = 1024;
    __shared__ __align__(16) ushort As[64 * 64];    //  8 KB, 512 chunks
    __shared__ __align__(16) ushort Bs[128 * 64];   // 16 KB, 1024 chunks

    int tid = threadIdx.x;
    int lane = tid & 63, w = tid >> 6;
    int l15 = lane & 15, q4 = lane >> 4;
    int wr = (w >> 1) * 32, wc = (w & 1) * 64;
    int rowBase = blockIdx.y * 64, colBase = blockIdx.x * 128;

    const ushort* src[6]; ushort* dstp[6];
#pragma unroll
    for (int i = 0; i < 6; i++) {
        int id = i * 256 + w * 64 + lane;  // 0..1535
        if (id < 512) {
            int r = id >> 3, l = (id & 7) ^ ((id >> 3) & 7);
            src[i] = A + (size_t)(rowBase + r) * K + l * 8;
            dstp[i] = &As[id * 8];
        } else {
            int idb = id - 512;
            int r = idb >> 3, l = (idb & 7) ^ ((idb >> 3) & 7);
            src[i] = Bt + (size_t)(colBase + r) * K + l * 8;
            dstp[i] = &Bs[idb * 8];
        }
    }

    f32x4 acc[2][4];
    f32x4 zero = {0.f, 0.f, 0.f, 0.f};
#pragma unroll
    for (int mi = 0; mi < 2; mi++)
#pragma unroll
        for (int ni = 0; ni < 4; ni++) acc[mi][ni] = zero;

    for (int kt = 0; kt < 16; kt++) {
        __syncthreads();
#pragma unroll
        for (int i = 0; i < 6; i++) {
            gload_lds16(src[i], dstp[i]);
            src[i] += 64;
        }
        __syncthreads();

#pragma unroll
        for (int kk = 0; kk < 2; kk++) {
            short8 aF[2], bF[4];
#pragma unroll
            for (int mi = 0; mi < 2; mi++) {
                int r = wr + mi * 16 + l15;
                aF[mi] = *(const short8*)&As[r * 64 + ((kk * 4 + q4) ^ (r & 7)) * 8];
            }
#pragma unroll
            for (int ni = 0; ni < 4; ni++) {
                int r = wc + ni * 16 + l15;
                bF[ni] = *(const short8*)&Bs[r * 64 + ((kk * 4 + q4) ^ (r & 7)) * 8];
            }
#pragma unroll
            for (int mi = 0; mi < 2; mi++)
#pragma unroll
                for (int ni = 0; ni < 4; ni++)
                    acc[mi][ni] = __builtin_amdgcn_mfma_f32_16x16x32_bf16(
                        aF[mi], bF[ni], acc[mi][ni], 0, 0, 0);
        }
    }

#pragma unroll
    for (int ni = 0; ni < 4; ni++) {
        int col = colBase + wc + ni * 16 + l15;
        float bv = bias[col];
#pragma unroll
        for (int mi = 0; mi < 2; mi++) {
            f32x4 a = acc[mi][ni];
#pragma unroll
            for (int r = 0; r < 4; r++) {
                int row = rowBase + wr + mi * 16 + q4 * 4 + r;
                outf[(size_t)row * 1024 + col] =
                    a[r] + bv + bf2f(resid[(size_t)row * 1024 + col]);
            }
        }
    }
}

// ---------------------------------------------------------------------------
// Attention v7: one block = (head g, 128 q-rows); 8 waves x 16q; 512 thr.
// One K/V staging serves 2x the compute of v4: per-thread staging gloads
// halve (8->4/kt) and per-head K/V re-staging halves (8 q-blocks vs 16).
// LDS 48 KB (Ks 16K + Vt 16K + Ps 16K).  Per-wave math identical to v4.
//  - Ks [64 key][128 d], XOR-16 chunk swizzle, global_load_lds staged
//  - Vt [128 d][64 key], XOR-8 chunk swizzle, global_load_lds staged
//  - Ps [128 q][64 key], XOR-8 chunk swizzle, wave-private rows
// ---------------------------------------------------------------------------
__global__ __launch_bounds__(512) void attn_kernel(
    const ushort* __restrict__ qb, const ushort* __restrict__ kb,
    const ushort* __restrict__ vt, ushort* __restrict__ ob) {
    int g = blockIdx.x >> 3;       // head 0..63
    int qblk = blockIdx.x & 7;     // 128-row q block
    const ushort* Qh = qb + (size_t)g * 131072;
    const ushort* Kh = kb + (size_t)g * 131072;
    const ushort* Vh = vt + (size_t)g * 131072;  // [128 d][1024 key]

    __shared__ __align__(16) ushort Ks[64 * 128];   // 16 KB
    __shared__ __align__(16) ushort Vt[128 * 64];   // 16 KB
    __shared__ __align__(16) ushort Ps[128 * 64];   // 16 KB

    int tid = threadIdx.x, lane = tid & 63, w = tid >> 6;  // w in [0,8)
    int l15 = lane & 15, q4 = lane >> 4;
    int q0 = qblk * 128;

    // Q A-fragments: A[m=l15][k = ks*32 + q4*8 + j]
    short8 qf[4];
#pragma unroll
    for (int ks = 0; ks < 4; ks++)
        qf[ks] = *(const short8*)&Qh[(size_t)(q0 + w * 16 + l15) * 128 + ks * 32 + q4 * 8];

    f32x4 zero = {0.f, 0.f, 0.f, 0.f};
    f32x4 o[8];
#pragma unroll
    for (int ni = 0; ni < 8; ni++) o[ni] = zero;
    float plsum[4] = {0.f, 0.f, 0.f, 0.f};

    for (int kt = 0; kt < 16; kt++) {
        __syncthreads();
        // Ks: phys chunk p in key-row r holds logical chunk l = p ^ (r&15)
#pragma unroll
        for (int i = 0; i < 2; i++) {
            int linear = i * 512 + tid;          // 0..1023, wave-contiguous
            int r = linear >> 4, p = linear & 15;
            int l = p ^ (r & 15);
            gload_lds16(&Kh[(size_t)(kt * 64 + r) * 128 + l * 8], &Ks[linear * 8]);
        }
        // Vt: phys chunk p in d-row holds logical chunk c = p ^ (d&7)
#pragma unroll
        for (int i = 0; i < 2; i++) {
            int linear = i * 512 + tid;          // 0..1023
            int d = linear >> 3, p = linear & 7;
            int c = p ^ (d & 7);
            gload_lds16(&Vh[(size_t)d * 1024 + kt * 64 + c * 8], &Vt[linear * 8]);
        }
        __syncthreads();

        // S = Q K^T : 16q x 64key per wave
        f32x4 sacc[4];
#pragma unroll
        for (int ni = 0; ni < 4; ni++) sacc[ni] = zero;
#pragma unroll
        for (int ks = 0; ks < 4; ks++) {
#pragma unroll
            for (int ni = 0; ni < 4; ni++) {
                int r = ni * 16 + l15;
                int p = (ks * 4 + q4) ^ (r & 15);
                short8 bF = *(const short8*)&Ks[r * 128 + p * 8];
                sacc[ni] = __builtin_amdgcn_mfma_f32_16x16x32_bf16(
                    qf[ks], bF, sacc[ni], 0, 0, 0);
            }
        }

        // P = exp(S) -> Ps (swizzled); accumulate per-lane partial row sums
#pragma unroll
        for (int ni = 0; ni < 4; ni++) {
#pragma unroll
            for (int r = 0; r < 4; r++) {
                float pv = __expf(sacc[ni][r]);
                plsum[r] += pv;
                int qloc = w * 16 + q4 * 4 + r;       // wave-private rows
                int key = ni * 16 + l15;
                int pc = (key >> 3) ^ (qloc & 7);
                Ps[qloc * 64 + pc * 8 + (key & 7)] = f2bf(pv);
            }
        }

        // O += P V  (wave-private Ps rows; same-wave RAW handled by waitcnt)
#pragma unroll
        for (int ks2 = 0; ks2 < 2; ks2++) {
            int c = ks2 * 4 + q4;
            int row = w * 16 + l15;                   // row&7 == l15&7
            short8 aF = *(const short8*)&Ps[row * 64 + (c ^ (l15 & 7)) * 8];
#pragma unroll
            for (int ni = 0; ni < 8; ni++) {
                int d = ni * 16 + l15;
                short8 bF = *(const short8*)&Vt[d * 64 + (c ^ (d & 7)) * 8];
                o[ni] = __builtin_amdgcn_mfma_f32_16x16x32_bf16(aF, bF, o[ni], 0, 0, 0);
            }
        }
    }

    // row sums: reduce per-lane partials over the 16 l15-lanes
#pragma unroll
    for (int r = 0; r < 4; r++) {
#pragma unroll
        for (int m = 1; m < 16; m <<= 1) plsum[r] += __shfl_xor(plsum[r], m, 16);
    }
    float inv[4];
#pragma unroll
    for (int r = 0; r < 4; r++) inv[r] = 1.0f / plsum[r];
#pragma unroll
    for (int ni = 0; ni < 8; ni++)
#pragma unroll
        for (int r = 0; r < 4; r++) {
            int qrow = q0 + w * 16 + q4 * 4 + r;
            ob[(size_t)g * 131072 + (size_t)qrow * 128 + ni * 16 + l15] =
                f2bf(o[ni][r] * inv[r]);
        }
}

// ---------------------------------------------------------------------------
extern "C" void kernel_launch(void* const* d_in, const int* in_sizes, int n_in,
                              void* d_out, int out_size, void* d_ws, size_t ws_size,
                              hipStream_t stream) {
    const float* x     = (const float*)d_in[0];
    const float* ln_g  = (const float*)d_in[1];
    const float* ln_b  = (const float*)d_in[2];
    const float* w_qkv = (const float*)d_in[3];
    const float* b_qkv = (const float*)d_in[4];
    const float* w_out = (const float*)d_in[5];
    const float* b_out = (const float*)d_in[6];
    float* out = (float*)d_out;

    const size_t MC = 8192ull * 1024ull;  // 8.39M elems
    ushort* xn    = (ushort*)d_ws;
    ushort* wqkvT = xn + MC;
    ushort* woutT = wqkvT + 3072ull * 1024ull;
    ushort* qbuf  = woutT + 1024ull * 1024ull;
    ushort* kbuf  = qbuf + MC;
    ushort* vtbuf = kbuf + MC;        // V^T [64 heads][128 d][1024 seq]
    ushort* attnb = vtbuf + MC;       // scratch for raw V, then attn output
    // total: 46.14M ushorts = 92.3 MB (same layout as passing rounds 2-10)

    prep_kernel<<<6144, 256, 0, stream>>>(x, ln_g, ln_b, xn, w_qkv, wqkvT, w_out, woutT);
    // q,k -> qbuf,kbuf ; v -> attnb (scratch, row-major coalesced)
    gemm_qkv<<<dim3(24, 64), 256, 0, stream>>>(xn, wqkvT, b_qkv, qbuf, kbuf, attnb);
    transpose_head<<<dim3(4, 32, 64), 256, 0, stream>>>(attnb, vtbuf);
    attn_kernel<<<512, 512, 0, stream>>>(qbuf, kbuf, vtbuf, attnb);
    gemm_out<<<dim3(8, 128), 256, 0, stream>>>(attnb, woutT, b_out, xn, out);
}